// Round 3
// baseline (277.290 us; speedup 1.0000x reference)
//
#include <hip/hip_runtime.h>
#include <math.h>

#define T_SEQ 34
#define VOCAB 14
#define NE (T_SEQ * VOCAB)      // 476 distinct (t, token) states
#define SEQS 64                  // sequences per block
#define BLK 576                  // 9 waves: lane=seq, wave=t-group
#define NBLK 1024                // 65536 / 64
#define OFFP 35                  // padded stride for offt (odd -> conflict-free)

__device__ __forceinline__ void layernorm6(const float* x, const float* g,
                                           const float* bt, float* o) {
    float mu = (x[0] + x[1] + x[2] + x[3] + x[4] + x[5]) * (1.0f / 6.0f);
    float var = 0.0f;
#pragma unroll
    for (int i = 0; i < 6; ++i) { float d = x[i] - mu; var += d * d; }
    var *= (1.0f / 6.0f);
    float rs = rsqrtf(var + 1e-5f);
#pragma unroll
    for (int i = 0; i < 6; ++i) o[i] = (x[i] - mu) * rs * g[i] + bt[i];
}

// Attention + epilogue for NT consecutive t-values [T0, T0+NT) of one sequence.
template <int NT>
__device__ __forceinline__ void run_rows(
    int T0, int seq, int blk,
    const float4* __restrict__ kvA, const float4* __restrict__ kvB,
    const float4* __restrict__ kvC,
    const float4* __restrict__ qA,  const float2* __restrict__ qB,
    const float4* __restrict__ xA,  const float2* __restrict__ xB,
    const int* __restrict__ myoff,
    const float* __restrict__ wo,
    const float* __restrict__ ln2_g, const float* __restrict__ ln2_b,
    const float* __restrict__ w1,   const float* __restrict__ b1,
    const float* __restrict__ w2,   const float* __restrict__ b2,
    const float* __restrict__ lnf_g, const float* __restrict__ lnf_b,
    const float* __restrict__ w_head,
    float* __restrict__ out)
{
    float q[NT][6];
#pragma unroll
    for (int i = 0; i < NT; ++i) {
        const int e = myoff[T0 + i];
        const float4 a = qA[e]; const float2 b2v = qB[e];
        q[i][0] = a.x; q[i][1] = a.y; q[i][2] = a.z;
        q[i][3] = a.w; q[i][4] = b2v.x; q[i][5] = b2v.y;
    }
    float den0[NT], den1[NT], acc[NT][6];
#pragma unroll
    for (int i = 0; i < NT; ++i) {
        den0[i] = 0.f; den1[i] = 0.f;
#pragma unroll
        for (int j = 0; j < 6; ++j) acc[i][j] = 0.f;
    }

    // one kv read serves all NT queries; imin is compile-time at all call sites
    auto body = [&](int e, int imin) {
        const float4 ea = kvA[e], eb = kvB[e], ec = kvC[e];
#pragma unroll
        for (int i = 0; i < NT; ++i) {
            if (i >= imin) {
                const float s0 = q[i][0] * ea.x + q[i][1] * ea.y + q[i][2] * ea.z;
                const float s1 = q[i][3] * ea.w + q[i][4] * eb.x + q[i][5] * eb.y;
                const float p0 = exp2f(s0);   // k pre-scaled by log2e/sqrt(3)
                const float p1 = exp2f(s1);
                den0[i] += p0; den1[i] += p1;
                acc[i][0] += p0 * eb.z; acc[i][1] += p0 * eb.w; acc[i][2] += p0 * ec.x;
                acc[i][3] += p1 * ec.y; acc[i][4] += p1 * ec.z; acc[i][5] += p1 * ec.w;
            }
        }
    };

    for (int s = 0; s < T0; ++s) body(myoff[s], 0);   // full trips: all NT t's
#pragma unroll
    for (int j = 0; j < NT; ++j) body(myoff[T0 + j], j);  // static causal tail

    // ---- epilogue per t ----
#pragma unroll
    for (int i = 0; i < NT; ++i) {
        const int t = T0 + i;
        const int e = myoff[t];
        const float inv0 = __builtin_amdgcn_rcpf(den0[i]);
        const float inv1 = __builtin_amdgcn_rcpf(den1[i]);
        float ao[6];
#pragma unroll
        for (int d = 0; d < 3; ++d) { ao[d] = acc[i][d] * inv0; ao[3 + d] = acc[i][3 + d] * inv1; }
        const float4 xa = xA[e]; const float2 xb = xB[e];
        const float x[6] = {xa.x, xa.y, xa.z, xa.w, xb.x, xb.y};
        float x2[6];
#pragma unroll
        for (int j = 0; j < 6; ++j) {
            float s = x[j];
#pragma unroll
            for (int k = 0; k < 6; ++k) s += ao[k] * wo[k * 6 + j];
            x2[j] = s;
        }
        float h[6];
        layernorm6(x2, ln2_g, ln2_b, h);
        float f[6];
#pragma unroll
        for (int j = 0; j < 6; ++j) {
            float s = b1[j];
#pragma unroll
            for (int k = 0; k < 6; ++k) s += h[k] * w1[k * 6 + j];
            f[j] = 0.5f * s * (1.0f + erff(s * 0.70710678118654752f));
        }
        float x3[6];
#pragma unroll
        for (int j = 0; j < 6; ++j) {
            float s = x2[j] + b2[j];
#pragma unroll
            for (int k = 0; k < 6; ++k) s += f[k] * w2[k * 6 + j];
            x3[j] = s;
        }
        float xo[6];
        layernorm6(x3, lnf_g, lnf_b, xo);

        const size_t g = ((size_t)(blk * SEQS + seq)) * T_SEQ + t;
        float2* op = (float2*)(out + g * 14);
#pragma unroll
        for (int jj = 0; jj < 7; ++jj) {
            float o0 = 0.f, o1 = 0.f;
#pragma unroll
            for (int k = 0; k < 6; ++k) {
                o0 += xo[k] * w_head[k * 14 + 2 * jj];
                o1 += xo[k] * w_head[k * 14 + 2 * jj + 1];
            }
            op[jj] = make_float2(o0, o1);
        }
    }
}

__global__ __launch_bounds__(BLK, 5) void fused_tf_kernel(
    const int* __restrict__ idx,
    const float* __restrict__ tok_emb,
    const float* __restrict__ pos_enc,
    const float* __restrict__ wq,
    const float* __restrict__ wk,
    const float* __restrict__ wv,
    const float* __restrict__ wo,
    const float* __restrict__ ln1_g, const float* __restrict__ ln1_b,
    const float* __restrict__ ln2_g, const float* __restrict__ ln2_b,
    const float* __restrict__ w1,   const float* __restrict__ b1,
    const float* __restrict__ w2,   const float* __restrict__ b2,
    const float* __restrict__ lnf_g, const float* __restrict__ lnf_b,
    const float* __restrict__ w_head,
    float* __restrict__ out)
{
    // SoA planes over the 476 (t,token) states; float4/float2 strides give
    // <=2-way bank aliasing (free) with same-address broadcast for equal toks.
    __shared__ float4 kvA[NE];   // k0x k0y k0z k1x   (k pre-scaled log2e/sqrt3)
    __shared__ float4 kvB[NE];   // k1y k1z v0x v0y
    __shared__ float4 kvC[NE];   // v0z v1x v1y v1z
    __shared__ float4 qA[NE];    // q0x q0y q0z q1x
    __shared__ float2 qB[NE];    // q1y q1z
    __shared__ float4 xA[NE];    // x0..x3 (pre-LN residual)
    __shared__ float2 xB[NE];    // x4 x5
    __shared__ int offt[SEQS * OFFP];   // table index per (seq, s)

    const int tid = threadIdx.x;

    // ---- stage idx -> table indices (coalesced global reads) ----
    for (int i = tid; i < SEQS * T_SEQ; i += BLK) {
        const int sq = i / T_SEQ;
        const int s  = i - sq * T_SEQ;
        const int tok = idx[(size_t)blockIdx.x * (SEQS * T_SEQ) + i];
        offt[sq * OFFP + s] = s * VOCAB + tok;
    }

    // ---- build the 476-state tables ----
    if (tid < NE) {
        const int t = tid / VOCAB;
        const int v = tid - t * VOCAB;
        float x[6];
#pragma unroll
        for (int i = 0; i < 3; ++i) x[i] = tok_emb[v * 3 + i];
#pragma unroll
        for (int i = 0; i < 3; ++i) x[3 + i] = pos_enc[t * 3 + i];
        float xl[6];
        layernorm6(x, ln1_g, ln1_b, xl);
        const float kscale = 0.8329812666744317f;  // log2(e)/sqrt(3)
        float qv[6], kv6[6], vv[6];
#pragma unroll
        for (int j = 0; j < 6; ++j) {
            qv[j]  =  xl[3] * wq[j] + xl[4] * wq[6 + j] + xl[5] * wq[12 + j];
            kv6[j] = (xl[3] * wk[j] + xl[4] * wk[6 + j] + xl[5] * wk[12 + j]) * kscale;
            vv[j]  =  xl[0] * wv[j] + xl[1] * wv[6 + j] + xl[2] * wv[12 + j];
        }
        kvA[tid] = make_float4(kv6[0], kv6[1], kv6[2], kv6[3]);
        kvB[tid] = make_float4(kv6[4], kv6[5], vv[0], vv[1]);
        kvC[tid] = make_float4(vv[2], vv[3], vv[4], vv[5]);
        qA[tid]  = make_float4(qv[0], qv[1], qv[2], qv[3]);
        qB[tid]  = make_float2(qv[4], qv[5]);
        xA[tid]  = make_float4(x[0], x[1], x[2], x[3]);
        xB[tid]  = make_float2(x[4], x[5]);
    }
    __syncthreads();

    const int seq = tid & 63;       // lane = sequence -> uniform waves
    const int grp = tid >> 6;       // wave = t-group
    const int* myoff = &offt[seq * OFFP];

    if (grp < 8)
        run_rows<4>(4 * grp, seq, blockIdx.x, kvA, kvB, kvC, qA, qB, xA, xB,
                    myoff, wo, ln2_g, ln2_b, w1, b1, w2, b2, lnf_g, lnf_b,
                    w_head, out);
    else
        run_rows<2>(32, seq, blockIdx.x, kvA, kvB, kvC, qA, qB, xA, xB,
                    myoff, wo, ln2_g, ln2_b, w1, b1, w2, b2, lnf_g, lnf_b,
                    w_head, out);
}

extern "C" void kernel_launch(void* const* d_in, const int* in_sizes, int n_in,
                              void* d_out, int out_size, void* d_ws, size_t ws_size,
                              hipStream_t stream) {
    const int*   idx     = (const int*)d_in[0];
    const float* tok_emb = (const float*)d_in[1];
    const float* pos_enc = (const float*)d_in[2];
    const float* wq      = (const float*)d_in[3];
    const float* wk      = (const float*)d_in[4];
    const float* wv      = (const float*)d_in[5];
    const float* wo      = (const float*)d_in[6];
    const float* ln1_g   = (const float*)d_in[7];
    const float* ln1_b   = (const float*)d_in[8];
    const float* ln2_g   = (const float*)d_in[9];
    const float* ln2_b   = (const float*)d_in[10];
    const float* w1      = (const float*)d_in[11];
    const float* b1      = (const float*)d_in[12];
    const float* w2      = (const float*)d_in[13];
    const float* b2      = (const float*)d_in[14];
    const float* lnf_g   = (const float*)d_in[15];
    const float* lnf_b   = (const float*)d_in[16];
    const float* w_head  = (const float*)d_in[17];
    float* out = (float*)d_out;

    hipLaunchKernelGGL(fused_tf_kernel, dim3(NBLK), dim3(BLK), 0, stream,
                       idx, tok_emb, pos_enc, wq, wk, wv, wo,
                       ln1_g, ln1_b, ln2_g, ln2_b, w1, b1, w2, b2,
                       lnf_g, lnf_b, w_head, out);
}